// Round 3
// baseline (226.043 us; speedup 1.0000x reference)
//
#include <hip/hip_runtime.h>
#include <hip/hip_bf16.h>
#include <stdint.h>

// T=1024, D=4096, O=4096, R=16, L=16. fp32 device buffers.
// R9 LESSON: device-scope fence per block = L2 writeback on gfx950 -> 6x
//   serialization; separate epilogue launch wins.
// R10: merged K1/K2a (2048-block k12), 191 us.
// R11/R12 NULL: moving scratch out of d_in[0/1] changed nothing (190.4).
//   Input-clobbering is free; harness overhead is fixed. Lever = kernel time.
// R13: fuse W fp32->bf16 into k12's B-staging (W is read EXACTLY once, so
//   pre-converting it is a pure 96 MB round-trip waste).
//   - k12 main: B reg-staged from fp32 W (2x dwordx4 -> cvt -> ds_write_b128,
//     same XOR-swizzled slot layout); A stays global_load_lds from xb.
//   - convert now only x/la/lb: 132 MB -> 36 MB traffic.
//   - ws layout no longer holds wb: xb(8)+ab(2)+lbb(2)+partial(32) = 44 MB,
//     inside the proven >=46.1 MB budget. a_part -> d_in[0] (proven clobber).
//   Predict: k12 45 -> 50-56 us (FETCH 61->93 MB), convert ~7 us,
//   dur_us 190 -> ~170-180.
#define T_TOK 1024
#define D_IN  4096
#define O_OUT 4096
#define RANK  16

#define BM 128
#define BN 128
#define BKM 64                 // main-GEMM K-tile
#define PART_ELEMS 4194304     // 1024*4096 per K-chunk partial (bf16)
#define APART_STRIDE 262144    // 1024*256 per shrink K-chunk (fp32)

typedef __bf16 bf16;
typedef __bf16 bf16x4 __attribute__((ext_vector_type(4)));
typedef __bf16 bf16x8 __attribute__((ext_vector_type(8)));
typedef float  v4f    __attribute__((ext_vector_type(4)));

// ws layout (bytes) — 44 MB total, within proven budget
#define WS_XB    0          // x  bf16 [1024,4096]          8 MB
#define WS_AB    8388608    // A_all bf16 [256,4096]        2 MB
#define WS_LBB   10485760   // lora_b bf16 [16,4096,16]     2 MB
#define WS_PART  12582912   // partial bf16 [4][1024][4096] 32 MB

#define ASYNC_COPY16(gptr, lptr)                                                   \
  __builtin_amdgcn_global_load_lds((const __attribute__((address_space(1))) void*)(gptr), \
                                   (__attribute__((address_space(3))) void*)(lptr), 16, 0, 0)

__device__ inline bf16x8 cvt_pack8(v4f a, v4f b) {
    bf16x8 r;
    r[0] = (bf16)a[0]; r[1] = (bf16)a[1]; r[2] = (bf16)a[2]; r[3] = (bf16)a[3];
    r[4] = (bf16)b[0]; r[5] = (bf16)b[1]; r[6] = (bf16)b[2]; r[7] = (bf16)b[3];
    return r;
}

// ---------------------------------------------------------------------------
// K0: fp32 -> bf16 convert of x, A_all, lora_b (W is converted in-GEMM now).
// 786432 chunks of 8 elems = 3072 blocks.
// ---------------------------------------------------------------------------
__global__ __launch_bounds__(256) void convert_kernel(
    const float* __restrict__ x, const float* __restrict__ la,
    const float* __restrict__ lb,
    bf16* __restrict__ xb, bf16* __restrict__ ab, bf16* __restrict__ lbb)
{
    const int c = blockIdx.x * 256 + threadIdx.x;
    const float* src; bf16* dst; int off;
    if (c < 524288)       { src = x;  dst = xb;  off = c; }
    else if (c < 655360)  { src = la; dst = ab;  off = c - 524288; }
    else                  { src = lb; dst = lbb; off = c - 655360; }
    const size_t e = (size_t)off * 8;
    v4f lo = *(const v4f*)&src[e];
    v4f hi = *(const v4f*)&src[e + 4];
    *(bf16x8*)&dst[e] = cvt_pack8(lo, hi);
}

// ---------------------------------------------------------------------------
// K12: merged launch, 2048 blocks.
//  blocks [0,1024):    main-GEMM partial  part[kc][t][o] += x@W^T (K-chunk)
//                      A: global_load_lds from xb (bf16).
//                      B: reg-staged from W fp32 with in-flight cvt to bf16,
//                         written to the SAME XOR-swizzled slots as before.
//  blocks [1024,2048): shrink partial a_part[kc][t][n] = x@A_all^T (K-chunk)
// ---------------------------------------------------------------------------
__global__ __launch_bounds__(256, 4) void k12_kernel(
    const bf16* __restrict__ xb, const float* __restrict__ wgt,
    const bf16* __restrict__ ab, bf16* __restrict__ part,
    float* __restrict__ a_part)
{
    __shared__ __align__(16) bf16 sA[BM * BKM];   // 16 KB
    __shared__ __align__(16) bf16 sB[BN * BKM];   // 16 KB

    const int tid = threadIdx.x, wid = tid >> 6, lane = tid & 63;
    const int bid = blockIdx.x;

    if (bid < 1024) {
        // ---------------- main GEMM partial ----------------
        const int bn = bid & 31, bm = (bid >> 5) & 7, kc = bid >> 8;

        const bf16*  __restrict__ gA = xb  + (size_t)bm * BM * D_IN + kc * 1024;
        const float* __restrict__ gW = wgt + (size_t)bn * BN * D_IN + kc * 1024;

        const int wm = (wid & 1) * 64, wn = (wid >> 1) * 64;
        const int lrow = lane & 15, quad = lane >> 4;

        v4f acc[4][4];
        const v4f vz = {0.f, 0.f, 0.f, 0.f};
#pragma unroll
        for (int mi = 0; mi < 4; ++mi)
#pragma unroll
            for (int ni = 0; ni < 4; ++ni) acc[mi][ni] = vz;

        for (int k0 = 0; k0 < 1024; k0 += BKM) {
            // slot s: row=s>>3, pos=s&7 holds global k-chunk pos^(row&7)
#pragma unroll
            for (int it = 0; it < 4; ++it) {
                const int s   = wid * 64 + lane + it * 256;
                const int row = s >> 3, pos = s & 7;
                const int kc8 = pos ^ (row & 7);
                const size_t goff = (size_t)row * D_IN + k0 + kc8 * 8;
                // A: async direct-to-LDS (dest = wave-uniform base, HW adds lane*16)
                char* la_ = (char*)sA + (size_t)(wid * 64 + it * 256) * 16;
                ASYNC_COPY16(gA + goff, la_);
                // B: fp32 load + cvt + swizzled ds_write (slot s, 16B)
                const float* gw = gW + goff;
                v4f lo = *(const v4f*)gw;
                v4f hi = *(const v4f*)(gw + 4);
                *(bf16x8*)((char*)sB + (size_t)s * 16) = cvt_pack8(lo, hi);
            }
            __syncthreads();

#pragma unroll
            for (int ks = 0; ks < 2; ++ks) {
                bf16x8 af[4], bfv[4];
#pragma unroll
                for (int mi = 0; mi < 4; ++mi) {
                    const int row = wm + mi * 16 + lrow;
                    const int pos = (ks * 4 + quad) ^ (row & 7);
                    af[mi] = *(const bf16x8*)&sA[row * BKM + pos * 8];
                }
#pragma unroll
                for (int ni = 0; ni < 4; ++ni) {
                    const int row = wn + ni * 16 + lrow;
                    const int pos = (ks * 4 + quad) ^ (row & 7);
                    bfv[ni] = *(const bf16x8*)&sB[row * BKM + pos * 8];
                }
#pragma unroll
                for (int mi = 0; mi < 4; ++mi)
#pragma unroll
                    for (int ni = 0; ni < 4; ++ni)
                        acc[mi][ni] = __builtin_amdgcn_mfma_f32_16x16x32_bf16(
                            af[mi], bfv[ni], acc[mi][ni], 0, 0, 0);
            }
            __syncthreads();
        }

        bf16* __restrict__ op = part + (size_t)kc * PART_ELEMS;
        // C/D layout (16x16x32): col=lane&15, row=quad*4+reg
#pragma unroll
        for (int mi = 0; mi < 4; ++mi)
#pragma unroll
            for (int r = 0; r < 4; ++r) {
                const int t = bm * BM + wm + mi * 16 + quad * 4 + r;
#pragma unroll
                for (int ni = 0; ni < 4; ++ni) {
                    const int o = bn * BN + wn + ni * 16 + lrow;
                    op[(size_t)t * O_OUT + o] = (bf16)acc[mi][ni][r];
                }
            }
    } else {
        // ---------------- shrink GEMM partial ----------------
        const int b2 = bid - 1024;
        const int bm = b2 & 15, bn = (b2 >> 4) & 3, kc = b2 >> 6;

        bf16* sX = sA;                 // reuse first 4 KB of each buffer
        bf16* sAl = sB;

        const bf16* __restrict__ gX = xb + (size_t)bm * 64 * D_IN + kc * 256;
        const bf16* __restrict__ gA = ab + (size_t)bn * 64 * D_IN + kc * 256;

        const int wm = (wid & 1) * 32, wn = (wid >> 1) * 32;
        const int lrow = lane & 15, kq = (lane >> 4) * 8;
        const int row = tid >> 2, ch = tid & 3;

        v4f acc[2][2];
        const v4f vz = {0.f, 0.f, 0.f, 0.f};
        acc[0][0] = vz; acc[0][1] = vz; acc[1][0] = vz; acc[1][1] = vz;

        for (int k0 = 0; k0 < 256; k0 += 32) {
            const size_t goff = (size_t)row * D_IN + k0 + ch * 8;
            ASYNC_COPY16(gX + goff, (char*)sX + wid * 1024);
            ASYNC_COPY16(gA + goff, (char*)sAl + wid * 1024);
            __syncthreads();
            bf16x8 xf[2], af[2];
#pragma unroll
            for (int mi = 0; mi < 2; ++mi)
                xf[mi] = *(const bf16x8*)&sX[(wm + mi * 16 + lrow) * 32 + kq];
#pragma unroll
            for (int ni = 0; ni < 2; ++ni)
                af[ni] = *(const bf16x8*)&sAl[(wn + ni * 16 + lrow) * 32 + kq];
#pragma unroll
            for (int mi = 0; mi < 2; ++mi)
#pragma unroll
                for (int ni = 0; ni < 2; ++ni)
                    acc[mi][ni] = __builtin_amdgcn_mfma_f32_16x16x32_bf16(
                        xf[mi], af[ni], acc[mi][ni], 0, 0, 0);
            __syncthreads();
        }

        float* __restrict__ op = a_part + (size_t)kc * APART_STRIDE;
#pragma unroll
        for (int mi = 0; mi < 2; ++mi)
#pragma unroll
            for (int r = 0; r < 4; ++r) {
                const int t = bm * 64 + wm + mi * 16 + (lane >> 4) * 4 + r;
#pragma unroll
                for (int ni = 0; ni < 2; ++ni) {
                    const int n = bn * 64 + wn + ni * 16 + (lane & 15);
                    op[(size_t)t * 256 + n] = acc[mi][ni][r];
                }
            }
    }
}

// ---------------------------------------------------------------------------
// K3: out[t,o] = sum_kc part[kc][t][o] + bias[o] + LoRA expand.
// Grid (1024): one block per token; 16 o/thread (4 x v4f).
// ---------------------------------------------------------------------------
__global__ __launch_bounds__(256) void epilogue_kernel(
    const bf16* __restrict__ part, const float* __restrict__ bias,
    const bf16* __restrict__ lbb, const int* __restrict__ idx,
    const float* __restrict__ a_part, float* __restrict__ out)
{
    const int t   = blockIdx.x;
    const int tid = threadIdx.x;
    const int l   = idx[t];

    // Parallel a_part reduction: thread i in [0,256) = (kc=i>>4, r=i&15)
    __shared__ float sred[256];
    __shared__ float sa[RANK];
    {
        float v = 0.0f;
        if (l >= 0) {
            const int kc = tid >> 4, r = tid & 15;
            v = a_part[(size_t)kc * APART_STRIDE + (size_t)t * 256 + l * RANK + r];
        }
        sred[tid] = v;
    }
    __syncthreads();
    if (tid < RANK) {
        float v = 0.0f;
#pragma unroll
        for (int kc = 0; kc < 16; ++kc) v += sred[kc * 16 + tid];
        sa[tid] = v;
    }
    __syncthreads();

#pragma unroll
    for (int c = 0; c < 4; ++c) {
        const int o = c * 1024 + tid * 4;
        const size_t po = (size_t)t * O_OUT + o;
        v4f s = *(const v4f*)&bias[o];
#pragma unroll
        for (int p = 0; p < 4; ++p) {
            bf16x4 pv = *(const bf16x4*)&part[(size_t)p * PART_ELEMS + po];
#pragma unroll
            for (int j = 0; j < 4; ++j) s[j] += (float)pv[j];
        }
        if (l >= 0) {
#pragma unroll
            for (int j = 0; j < 4; ++j) {
                const bf16* bp = lbb + ((size_t)l * O_OUT + o + j) * RANK;
                bf16x8 b0 = *(const bf16x8*)bp;
                bf16x8 b1 = *(const bf16x8*)(bp + 8);
                float y = 0.0f;
#pragma unroll
                for (int r = 0; r < 8; ++r) y += sa[r] * (float)b0[r];
#pragma unroll
                for (int r = 0; r < 8; ++r) y += sa[8 + r] * (float)b1[r];
                s[j] += y;
            }
        }
        *(v4f*)&out[po] = s;
    }
}

extern "C" void kernel_launch(void* const* d_in, const int* in_sizes, int n_in,
                              void* d_out, int out_size, void* d_ws, size_t ws_size,
                              hipStream_t stream) {
    const float* x    = (const float*)d_in[0];   // [1024, 4096]
    const float* wgt  = (const float*)d_in[1];   // [4096, 4096]
    const float* bias = (const float*)d_in[2];   // [4096]
    const float* la   = (const float*)d_in[3];   // [16,1,16,4096] = [256,4096]
    const float* lb   = (const float*)d_in[4];   // [16,1,4096,16]
    const int*   idx  = (const int*)d_in[5];     // [1024]
    float* out = (float*)d_out;

    char* ws = (char*)d_ws;
    bf16* xb      = (bf16*)(ws + WS_XB);
    bf16* ab      = (bf16*)(ws + WS_AB);
    bf16* lbb     = (bf16*)(ws + WS_LBB);
    bf16* partial = (bf16*)(ws + WS_PART);

    // a_part: fp32 x (16 MB) -> fp32 a_part [16][1024][256] (16 MB exactly).
    // convert consumes x before k12 overwrites it (stream-ordered); W stays
    // live (k12 reads it fp32 now). Proven-safe clobber from R10; R11/R12
    // showed clobbering costs nothing.
    float* a_part = (float*)d_in[0];

    convert_kernel<<<dim3(3072), dim3(256), 0, stream>>>(
        x, la, lb, xb, ab, lbb);
    k12_kernel<<<dim3(2048), dim3(256), 0, stream>>>(
        xb, wgt, ab, partial, a_part);
    epilogue_kernel<<<dim3(T_TOK), dim3(256), 0, stream>>>(
        partial, bias, lbb, idx, a_part, out);
}

// Round 4
// 187.809 us; speedup vs baseline: 1.2036x; 1.2036x over previous
//
#include <hip/hip_runtime.h>
#include <hip/hip_bf16.h>
#include <stdint.h>

// T=1024, D=4096, O=4096, R=16, L=16. fp32 device buffers.
// R9:  device-scope fence per block -> 6x serialization; separate epilogue wins.
// R10: merged K1/K2a (2048-block k12), 191 us. k12=45us, MfmaUtil 33%.
// R11/R12 NULL: un-clobbering inputs changed nothing; harness cost is fixed.
// R13 FAILED (226us): fusing W fp32->bf16 into k12 B-staging serialized the
//   K-loop (reg-stage: load->vmcnt(0)->cvt->ds_write on critical path).
//   k12 45->106us, MfmaUtil 13%. Reg-staging w/o async pipeline loses; the
//   HIP compiler defeats counted-vmcnt prefetch at source (m131-m141 class).
// R14: revert to R12 GEMM structure; trim pure traffic instead:
//   (a) main-GEMM split-K 4->2: partial 32->16 MB (write+read).
//   (b) shrink writes ONLY the idx-selected lora's 16 values per token
//       (a_sel [16][1024][16] fp32, 1 MB) instead of all 256 (16 MB).
//       Selected col-group is 16-aligned -> exactly one ni tile matches.
//   Predict: k12 ~40-44us (WRITE 49->17MB), epilogue ~7us, dur ~176-183.
#define T_TOK 1024
#define D_IN  4096
#define O_OUT 4096
#define RANK  16

#define BM 128
#define BN 128
#define BKM 64                 // main-GEMM K-tile
#define KCH 2048               // main-GEMM K per split-K chunk (split-K=2)
#define PART_ELEMS 4194304     // 1024*4096 per K-chunk partial (bf16)
#define ASEL_STRIDE 16384      // 1024*16 per shrink K-chunk (fp32)

typedef __bf16 bf16;
typedef __bf16 bf16x4 __attribute__((ext_vector_type(4)));
typedef __bf16 bf16x8 __attribute__((ext_vector_type(8)));
typedef float  v4f    __attribute__((ext_vector_type(4)));

// ws layout (bytes) — 44.1 MB, within proven budget
#define WS_WB    0          // W  bf16 [4096,4096]        32 MB
#define WS_XB    33554432   // x  bf16 [1024,4096]         8 MB
#define WS_AB    41943040   // A_all bf16 [256,4096]       2 MB
#define WS_LBB   44040192   // lora_b bf16 [16,4096,16]    2 MB

#define ASYNC_COPY16(gptr, lptr)                                                   \
  __builtin_amdgcn_global_load_lds((const __attribute__((address_space(1))) void*)(gptr), \
                                   (__attribute__((address_space(3))) void*)(lptr), 16, 0, 0)

__device__ inline bf16x8 cvt_pack8(v4f a, v4f b) {
    bf16x8 r;
    r[0] = (bf16)a[0]; r[1] = (bf16)a[1]; r[2] = (bf16)a[2]; r[3] = (bf16)a[3];
    r[4] = (bf16)b[0]; r[5] = (bf16)b[1]; r[6] = (bf16)b[2]; r[7] = (bf16)b[3];
    return r;
}

// ---------------------------------------------------------------------------
// K0: fp32 -> bf16 convert of W, x, A_all, lora_b. One 8-elem chunk/thread.
// ---------------------------------------------------------------------------
__global__ __launch_bounds__(256) void convert_kernel(
    const float* __restrict__ w, const float* __restrict__ x,
    const float* __restrict__ la, const float* __restrict__ lb,
    bf16* __restrict__ wb, bf16* __restrict__ xb,
    bf16* __restrict__ ab, bf16* __restrict__ lbb)
{
    const int c = blockIdx.x * 256 + threadIdx.x;
    const float* src; bf16* dst; int off;
    if (c < 2097152)      { src = w;  dst = wb;  off = c; }
    else if (c < 2621440) { src = x;  dst = xb;  off = c - 2097152; }
    else if (c < 2752512) { src = la; dst = ab;  off = c - 2621440; }
    else                  { src = lb; dst = lbb; off = c - 2752512; }
    const size_t e = (size_t)off * 8;
    v4f lo = *(const v4f*)&src[e];
    v4f hi = *(const v4f*)&src[e + 4];
    *(bf16x8*)&dst[e] = cvt_pack8(lo, hi);
}

// ---------------------------------------------------------------------------
// K12: merged launch, 1536 blocks.
//  blocks [0,512):     main-GEMM partial  part[kc][t][o] = x@W^T (K-chunk,
//                      split-K=2). BK=64, XOR-swizzled LDS (0 conflicts).
//  blocks [512,1536):  shrink partial, masked write: only idx[t]'s lora
//                      columns land in a_sel[kc][t][0..15].
// ---------------------------------------------------------------------------
__global__ __launch_bounds__(256, 4) void k12_kernel(
    const bf16* __restrict__ xb, const bf16* __restrict__ wb,
    const bf16* __restrict__ ab, const int* __restrict__ idx,
    bf16* __restrict__ part, float* __restrict__ a_sel)
{
    __shared__ __align__(16) bf16 sA[BM * BKM];   // 16 KB
    __shared__ __align__(16) bf16 sB[BN * BKM];   // 16 KB

    const int tid = threadIdx.x, wid = tid >> 6, lane = tid & 63;
    const int bid = blockIdx.x;

    if (bid < 512) {
        // ---------------- main GEMM partial (split-K=2) ----------------
        const int bn = bid & 31, bm = (bid >> 5) & 7, kc = bid >> 8;  // kc in {0,1}

        const bf16* __restrict__ gA = xb + (size_t)bm * BM * D_IN + kc * KCH;
        const bf16* __restrict__ gB = wb + (size_t)bn * BN * D_IN + kc * KCH;

        const int wm = (wid & 1) * 64, wn = (wid >> 1) * 64;
        const int lrow = lane & 15, quad = lane >> 4;

        v4f acc[4][4];
        const v4f vz = {0.f, 0.f, 0.f, 0.f};
#pragma unroll
        for (int mi = 0; mi < 4; ++mi)
#pragma unroll
            for (int ni = 0; ni < 4; ++ni) acc[mi][ni] = vz;

        for (int k0 = 0; k0 < KCH; k0 += BKM) {
            // slot s: row=s>>3, pos=s&7 holds global k-chunk pos^(row&7)
#pragma unroll
            for (int it = 0; it < 4; ++it) {
                const int s   = wid * 64 + lane + it * 256;
                const int row = s >> 3, pos = s & 7;
                const int kc8 = pos ^ (row & 7);
                const size_t goff = (size_t)row * D_IN + k0 + kc8 * 8;
                char* la_ = (char*)sA + (size_t)(wid * 64 + it * 256) * 16;
                char* lb_ = (char*)sB + (size_t)(wid * 64 + it * 256) * 16;
                ASYNC_COPY16(gA + goff, la_);
                ASYNC_COPY16(gB + goff, lb_);
            }
            __syncthreads();

#pragma unroll
            for (int ks = 0; ks < 2; ++ks) {
                bf16x8 af[4], bfv[4];
#pragma unroll
                for (int mi = 0; mi < 4; ++mi) {
                    const int row = wm + mi * 16 + lrow;
                    const int pos = (ks * 4 + quad) ^ (row & 7);
                    af[mi] = *(const bf16x8*)&sA[row * BKM + pos * 8];
                }
#pragma unroll
                for (int ni = 0; ni < 4; ++ni) {
                    const int row = wn + ni * 16 + lrow;
                    const int pos = (ks * 4 + quad) ^ (row & 7);
                    bfv[ni] = *(const bf16x8*)&sB[row * BKM + pos * 8];
                }
#pragma unroll
                for (int mi = 0; mi < 4; ++mi)
#pragma unroll
                    for (int ni = 0; ni < 4; ++ni)
                        acc[mi][ni] = __builtin_amdgcn_mfma_f32_16x16x32_bf16(
                            af[mi], bfv[ni], acc[mi][ni], 0, 0, 0);
            }
            __syncthreads();
        }

        bf16* __restrict__ op = part + (size_t)kc * PART_ELEMS;
        // C/D layout (16x16x32): col=lane&15, row=quad*4+reg
#pragma unroll
        for (int mi = 0; mi < 4; ++mi)
#pragma unroll
            for (int r = 0; r < 4; ++r) {
                const int t = bm * BM + wm + mi * 16 + quad * 4 + r;
#pragma unroll
                for (int ni = 0; ni < 4; ++ni) {
                    const int o = bn * BN + wn + ni * 16 + lrow;
                    op[(size_t)t * O_OUT + o] = (bf16)acc[mi][ni][r];
                }
            }
    } else {
        // ---------------- shrink GEMM partial (masked write) ----------------
        const int b2 = bid - 512;
        const int bm = b2 & 15, bn = (b2 >> 4) & 3, kc = b2 >> 6;

        bf16* sX = sA;                 // reuse first 4 KB of each buffer
        bf16* sAl = sB;

        const bf16* __restrict__ gX = xb + (size_t)bm * 64 * D_IN + kc * 256;
        const bf16* __restrict__ gA = ab + (size_t)bn * 64 * D_IN + kc * 256;

        const int wm = (wid & 1) * 32, wn = (wid >> 1) * 32;
        const int lrow = lane & 15, kq = (lane >> 4) * 8;
        const int row = tid >> 2, ch = tid & 3;

        v4f acc[2][2];
        const v4f vz = {0.f, 0.f, 0.f, 0.f};
        acc[0][0] = vz; acc[0][1] = vz; acc[1][0] = vz; acc[1][1] = vz;

        for (int k0 = 0; k0 < 256; k0 += 32) {
            const size_t goff = (size_t)row * D_IN + k0 + ch * 8;
            ASYNC_COPY16(gX + goff, (char*)sX + wid * 1024);
            ASYNC_COPY16(gA + goff, (char*)sAl + wid * 1024);
            __syncthreads();
            bf16x8 xf[2], af[2];
#pragma unroll
            for (int mi = 0; mi < 2; ++mi)
                xf[mi] = *(const bf16x8*)&sX[(wm + mi * 16 + lrow) * 32 + kq];
#pragma unroll
            for (int ni = 0; ni < 2; ++ni)
                af[ni] = *(const bf16x8*)&sAl[(wn + ni * 16 + lrow) * 32 + kq];
#pragma unroll
            for (int mi = 0; mi < 2; ++mi)
#pragma unroll
                for (int ni = 0; ni < 2; ++ni)
                    acc[mi][ni] = __builtin_amdgcn_mfma_f32_16x16x32_bf16(
                        xf[mi], af[ni], acc[mi][ni], 0, 0, 0);
            __syncthreads();
        }

        // Masked C-write: n-tile (bn*64+wn+ni*16) is 16-aligned; it matches a
        // token's selected lora iff n-tile == idx[t]*16. Write rank element
        // (lane&15) of a_sel[kc][t][.] only then. 1 MB total vs 16 MB.
        float* __restrict__ op = a_sel + (size_t)kc * ASEL_STRIDE;
        const int colbase = bn * 64 + wn;
#pragma unroll
        for (int mi = 0; mi < 2; ++mi)
#pragma unroll
            for (int r = 0; r < 4; ++r) {
                const int t = bm * 64 + wm + mi * 16 + (lane >> 4) * 4 + r;
                const int l = idx[t];
                if (l >= 0) {
#pragma unroll
                    for (int ni = 0; ni < 2; ++ni) {
                        if (colbase + ni * 16 == l * 16)
                            op[(size_t)t * RANK + (lane & 15)] = acc[mi][ni][r];
                    }
                }
            }
    }
}

// ---------------------------------------------------------------------------
// K3: out[t,o] = part[0][t][o] + part[1][t][o] + bias[o] + LoRA expand.
// Grid (1024): one block per token; 16 o/thread (4 x v4f).
// ---------------------------------------------------------------------------
__global__ __launch_bounds__(256) void epilogue_kernel(
    const bf16* __restrict__ part, const float* __restrict__ bias,
    const bf16* __restrict__ lbb, const int* __restrict__ idx,
    const float* __restrict__ a_sel, float* __restrict__ out)
{
    const int t   = blockIdx.x;
    const int tid = threadIdx.x;
    const int l   = idx[t];

    // Parallel a_sel reduction: thread i in [0,256) = (kc=i>>4, r=i&15)
    __shared__ float sred[256];
    __shared__ float sa[RANK];
    {
        float v = 0.0f;
        if (l >= 0) {
            const int kc = tid >> 4, r = tid & 15;
            v = a_sel[(size_t)kc * ASEL_STRIDE + (size_t)t * RANK + r];
        }
        sred[tid] = v;
    }
    __syncthreads();
    if (tid < RANK) {
        float v = 0.0f;
#pragma unroll
        for (int kc = 0; kc < 16; ++kc) v += sred[kc * 16 + tid];
        sa[tid] = v;
    }
    __syncthreads();

#pragma unroll
    for (int c = 0; c < 4; ++c) {
        const int o = c * 1024 + tid * 4;
        const size_t po = (size_t)t * O_OUT + o;
        v4f s = *(const v4f*)&bias[o];
#pragma unroll
        for (int p = 0; p < 2; ++p) {
            bf16x4 pv = *(const bf16x4*)&part[(size_t)p * PART_ELEMS + po];
#pragma unroll
            for (int j = 0; j < 4; ++j) s[j] += (float)pv[j];
        }
        if (l >= 0) {
#pragma unroll
            for (int j = 0; j < 4; ++j) {
                const bf16* bp = lbb + ((size_t)l * O_OUT + o + j) * RANK;
                bf16x8 b0 = *(const bf16x8*)bp;
                bf16x8 b1 = *(const bf16x8*)(bp + 8);
                float y = 0.0f;
#pragma unroll
                for (int r = 0; r < 8; ++r) y += sa[r] * (float)b0[r];
#pragma unroll
                for (int r = 0; r < 8; ++r) y += sa[8 + r] * (float)b1[r];
                s[j] += y;
            }
        }
        *(v4f*)&out[po] = s;
    }
}

extern "C" void kernel_launch(void* const* d_in, const int* in_sizes, int n_in,
                              void* d_out, int out_size, void* d_ws, size_t ws_size,
                              hipStream_t stream) {
    const float* x    = (const float*)d_in[0];   // [1024, 4096]
    const float* wgt  = (const float*)d_in[1];   // [4096, 4096]
    const float* bias = (const float*)d_in[2];   // [4096]
    const float* la   = (const float*)d_in[3];   // [16,1,16,4096] = [256,4096]
    const float* lb   = (const float*)d_in[4];   // [16,1,4096,16]
    const int*   idx  = (const int*)d_in[5];     // [1024]
    float* out = (float*)d_out;

    char* ws = (char*)d_ws;
    bf16* wb  = (bf16*)(ws + WS_WB);
    bf16* xb  = (bf16*)(ws + WS_XB);
    bf16* ab  = (bf16*)(ws + WS_AB);
    bf16* lbb = (bf16*)(ws + WS_LBB);

    // Dead-input scratch (proven safe R10-R12; convert consumes both inputs
    // before k12 overwrites; stream-ordered; clobber cost measured ~0):
    //   fp32 W (64 MB) -> bf16 partial [2][1024][4096] (16 MB)
    //   fp32 x (16 MB) -> fp32 a_sel  [16][1024][16]   (1 MB)
    bf16*  partial = (bf16*)d_in[1];
    float* a_sel   = (float*)d_in[0];

    convert_kernel<<<dim3(11264), dim3(256), 0, stream>>>(
        wgt, x, la, lb, wb, xb, ab, lbb);
    k12_kernel<<<dim3(1536), dim3(256), 0, stream>>>(
        xb, wb, ab, idx, partial, a_sel);
    epilogue_kernel<<<dim3(T_TOK), dim3(256), 0, stream>>>(
        partial, bias, lbb, idx, a_sel, out);
}